// Round 1
// baseline (179.096 us; speedup 1.0000x reference)
//
#include <hip/hip_runtime.h>
#include <hip/hip_bf16.h>
#include <cstdint>
#include <cstddef>

#define MDIM 4096
#define NDIM 4096
#define KDIM 4096

#define BM 128
#define BN 128
#define BK 64

typedef __bf16 bf16_t;
typedef bf16_t bf16x8 __attribute__((ext_vector_type(8)));
typedef float f32x4 __attribute__((ext_vector_type(4)));

// Direct global->LDS DMA, 16B per lane. LDS dest must be lane-linear
// (wave-uniform base + lane*16) -- our layout is exactly that.
#define GLDS16(gsrc, ldst)                                                   \
    __builtin_amdgcn_global_load_lds(                                        \
        (__attribute__((address_space(1))) void*)(gsrc),                     \
        (__attribute__((address_space(3))) void*)(ldst), 16, 0, 0)

// ---------------- fp32 -> bf16 conversion pass ----------------
__global__ void cvt_f32_to_bf16(const float* __restrict__ src,
                                bf16_t* __restrict__ dst, int n) {
    int idx = (blockIdx.x * blockDim.x + threadIdx.x) * 8;
    int stride = gridDim.x * blockDim.x * 8;
    for (int i = idx; i < n; i += stride) {
        const float4* s = reinterpret_cast<const float4*>(src + i);
        float4 a = s[0];
        float4 b = s[1];
        bf16x8 o;
        o[0] = (bf16_t)a.x; o[1] = (bf16_t)a.y;
        o[2] = (bf16_t)a.z; o[3] = (bf16_t)a.w;
        o[4] = (bf16_t)b.x; o[5] = (bf16_t)b.y;
        o[6] = (bf16_t)b.z; o[7] = (bf16_t)b.w;
        *reinterpret_cast<bf16x8*>(dst + i) = o;
    }
}

// ---------------- bf16 NT-GEMM, m97 structure ----------------
// C[m,n] = relu(1 - beta + sum_k A[m,k]*B[n,k])
// A: [M][K] bf16 row-major, B: [N][K] bf16 row-major (weights as given).
// 128x128 tile, BK=64, 256 threads = 4 waves in 2x2, each wave owns 64x64
// (4x4 fragments of 16x16x32 MFMA).
__global__ void gemm_bt_bf16(const bf16_t* __restrict__ A,
                             const bf16_t* __restrict__ B,
                             const float* __restrict__ beta,
                             float* __restrict__ out) {
    __shared__ __align__(16) bf16_t sA[BM * BK];
    __shared__ __align__(16) bf16_t sB[BN * BK];

    const int tid  = threadIdx.x;
    const int wid  = tid >> 6;
    const int lane = tid & 63;
    const int wr   = wid >> 1;       // wave row (0..1)
    const int wc   = wid & 1;        // wave col (0..1)
    const int lrow = lane & 15;      // fragment row/col index
    const int kgrp = lane >> 4;      // k-group 0..3 (k-offset kgrp*8)

    const int brow = blockIdx.y * BM;
    const int bcol = blockIdx.x * BN;

    f32x4 acc[4][4];
#pragma unroll
    for (int i = 0; i < 4; ++i)
#pragma unroll
        for (int j = 0; j < 4; ++j)
            acc[i][j] = (f32x4){0.f, 0.f, 0.f, 0.f};

    const bf16_t* gA = A + (size_t)brow * KDIM;
    const bf16_t* gB = B + (size_t)bcol * KDIM;

    for (int kt = 0; kt < KDIM; kt += BK) {
        // stage 128x64 bf16 tiles: 4 issues x 256 threads x 16B each
#pragma unroll
        for (int i = 0; i < 4; ++i) {
            int g   = i * 256 + tid;
            int row = g >> 3;            // 8 threads per 64-elem row
            int col = (g & 7) << 3;
            GLDS16(gA + (size_t)row * KDIM + kt + col, sA + g * 8);
            GLDS16(gB + (size_t)row * KDIM + kt + col, sB + g * 8);
        }
        __syncthreads();   // emits s_waitcnt vmcnt(0) + s_barrier

#pragma unroll
        for (int ko = 0; ko < 2; ++ko) {
            bf16x8 av[4], bv[4];
#pragma unroll
            for (int mi = 0; mi < 4; ++mi)
                av[mi] = *reinterpret_cast<const bf16x8*>(
                    &sA[(wr * 64 + mi * 16 + lrow) * BK + ko * 32 + kgrp * 8]);
#pragma unroll
            for (int ni = 0; ni < 4; ++ni)
                bv[ni] = *reinterpret_cast<const bf16x8*>(
                    &sB[(wc * 64 + ni * 16 + lrow) * BK + ko * 32 + kgrp * 8]);
#pragma unroll
            for (int mi = 0; mi < 4; ++mi)
#pragma unroll
                for (int ni = 0; ni < 4; ++ni)
                    acc[mi][ni] = __builtin_amdgcn_mfma_f32_16x16x32_bf16(
                        av[mi], bv[ni], acc[mi][ni], 0, 0, 0);
        }
        __syncthreads();
    }

    // epilogue: relu(1 - beta + acc)
    const float bias = 1.0f - beta[0];
    float* outp = out + (size_t)(brow + wr * 64) * NDIM + bcol + wc * 64;
#pragma unroll
    for (int mi = 0; mi < 4; ++mi) {
#pragma unroll
        for (int ni = 0; ni < 4; ++ni) {
#pragma unroll
            for (int j = 0; j < 4; ++j) {
                int r = mi * 16 + kgrp * 4 + j;   // C/D: row=(lane>>4)*4+reg
                int c = ni * 16 + lrow;           //      col=lane&15
                float v = acc[mi][ni][j] + bias;
                outp[(size_t)r * NDIM + c] = fmaxf(v, 0.0f);
            }
        }
    }
}

// ---------------- fp32 fallback (only if ws too small) ----------------
__global__ void gemm_f32_fallback(const float* __restrict__ A,
                                  const float* __restrict__ B,
                                  const float* __restrict__ beta,
                                  float* __restrict__ out) {
    __shared__ float sA[16][17];
    __shared__ float sB[16][17];
    const int tx = threadIdx.x, ty = threadIdx.y;
    const int m = blockIdx.y * 16 + ty;
    const int n = blockIdx.x * 16 + tx;
    float acc = 0.f;
    for (int k0 = 0; k0 < KDIM; k0 += 16) {
        sA[ty][tx] = A[(size_t)m * KDIM + k0 + tx];
        sB[ty][tx] = B[(size_t)(blockIdx.x * 16 + ty) * KDIM + k0 + tx];
        __syncthreads();
#pragma unroll
        for (int k = 0; k < 16; ++k)
            acc += sA[ty][k] * sB[tx][k];
        __syncthreads();
    }
    float v = acc + 1.0f - beta[0];
    out[(size_t)m * NDIM + n] = fmaxf(v, 0.f);
}

extern "C" void kernel_launch(void* const* d_in, const int* in_sizes, int n_in,
                              void* d_out, int out_size, void* d_ws, size_t ws_size,
                              hipStream_t stream) {
    const float* x    = (const float*)d_in[0];
    const float* w    = (const float*)d_in[1];
    const float* beta = (const float*)d_in[2];
    float* out        = (float*)d_out;

    const size_t nelem = (size_t)MDIM * (size_t)KDIM;   // per matrix
    const size_t need  = 2 * nelem * sizeof(bf16_t);    // 64 MB

    if (ws_size >= need) {
        bf16_t* xb = (bf16_t*)d_ws;
        bf16_t* wb = xb + nelem;
        cvt_f32_to_bf16<<<2048, 256, 0, stream>>>(x, xb, (int)nelem);
        cvt_f32_to_bf16<<<2048, 256, 0, stream>>>(w, wb, (int)nelem);
        dim3 grid(NDIM / BN, MDIM / BM);
        gemm_bt_bf16<<<grid, 256, 0, stream>>>(xb, wb, beta, out);
    } else {
        dim3 grid(NDIM / 16, MDIM / 16);
        gemm_f32_fallback<<<grid, dim3(16, 16), 0, stream>>>(x, w, beta, out);
    }
}

// Round 2
// 159.511 us; speedup vs baseline: 1.1228x; 1.1228x over previous
//
#include <hip/hip_runtime.h>
#include <hip/hip_bf16.h>
#include <cstdint>
#include <cstddef>

#define MDIM 4096
#define NDIM 4096
#define KDIM 4096

#define BM 256
#define BN 256
#define BK 64
#define NT (KDIM / BK)   // 64 K-tiles

typedef __bf16 bf16_t;
typedef bf16_t bf16x8 __attribute__((ext_vector_type(8)));
typedef float f32x4 __attribute__((ext_vector_type(4)));

#define GLDS16(gsrc, ldst)                                                   \
    __builtin_amdgcn_global_load_lds(                                        \
        (__attribute__((address_space(1))) void*)(gsrc),                     \
        (__attribute__((address_space(3))) void*)(ldst), 16, 0, 0)

#define BAR()   __builtin_amdgcn_s_barrier()
#define LGKM0() asm volatile("s_waitcnt lgkmcnt(0)" ::: "memory")
#define VM4()   asm volatile("s_waitcnt vmcnt(4)" ::: "memory")
#define VM0()   asm volatile("s_waitcnt vmcnt(0)" ::: "memory")

// st_16x32 swizzle: XOR byte-bit-5 with byte-bit-9 (involution, period 1024B)
__device__ __forceinline__ int swz(int q) { return q ^ (((q >> 9) & 1) << 5); }

// ---------------- fp32 -> bf16 conversion pass ----------------
__global__ void cvt_f32_to_bf16(const float* __restrict__ src,
                                bf16_t* __restrict__ dst, int n) {
    int idx = (blockIdx.x * blockDim.x + threadIdx.x) * 8;
    int stride = gridDim.x * blockDim.x * 8;
    for (int i = idx; i < n; i += stride) {
        const float4* s = reinterpret_cast<const float4*>(src + i);
        float4 a = s[0];
        float4 b = s[1];
        bf16x8 o;
        o[0] = (bf16_t)a.x; o[1] = (bf16_t)a.y;
        o[2] = (bf16_t)a.z; o[3] = (bf16_t)a.w;
        o[4] = (bf16_t)b.x; o[5] = (bf16_t)b.y;
        o[6] = (bf16_t)b.z; o[7] = (bf16_t)b.w;
        *reinterpret_cast<bf16x8*>(dst + i) = o;
    }
}

// ---------------- 256x256 8-phase bf16 NT-GEMM ----------------
// C[m,n] = relu(1 - beta + sum_k A[m,k]*B[n,k]); A,B row-major [4096][4096] bf16.
// 512 threads = 8 waves (2M x 4N); each wave owns 128x64 output (8x4 frags of
// 16x16). LDS 128 KB: 2 dbuf x 4 half-slots (A0,A1,B0,B1) x 128x64 bf16.
// Per K-tile: 4 phases; per phase: {ds_reads, 1 half-tile stage, BAR, lgkm0,
// setprio(1), 16 MFMA, setprio(0), [vmcnt(4) @P4], BAR}.
// Rolling prefetch, window t stages: P1:A1(t+1) P2:B1(t+1) P3:B0(t+2) P4:A0(t+2).

#define LOAD_A_HALF(MH, BUF) do {                                            \
  _Pragma("unroll") for (int mi = 0; mi < 4; ++mi)                           \
  _Pragma("unroll") for (int ko = 0; ko < 2; ++ko)                           \
    av[mi][ko] = *(const bf16x8*)(ldsb + ((BUF) << 16) + a_off[(MH)*4 + mi][ko]); \
} while (0)

#define LOAD_B_PAIR(NH, BUF) do {                                            \
  _Pragma("unroll") for (int ni = 0; ni < 2; ++ni)                           \
  _Pragma("unroll") for (int ko = 0; ko < 2; ++ko)                           \
    bv[(NH)*2 + ni][ko] = *(const bf16x8*)(ldsb + ((BUF) << 16) + b_off[(NH)*2 + ni][ko]); \
} while (0)

#define MFMA_QUAD(MH, NH) do {                                               \
  _Pragma("unroll") for (int mi = 0; mi < 4; ++mi)                           \
  _Pragma("unroll") for (int ni = 0; ni < 2; ++ni)                           \
  _Pragma("unroll") for (int ko = 0; ko < 2; ++ko)                           \
    acc[(MH)*4 + mi][(NH)*2 + ni] = __builtin_amdgcn_mfma_f32_16x16x32_bf16( \
        av[mi][ko], bv[(NH)*2 + ni][ko], acc[(MH)*4 + mi][(NH)*2 + ni], 0, 0, 0); \
} while (0)

__global__ __launch_bounds__(512, 2) void gemm256(const bf16_t* __restrict__ A,
                                                  const bf16_t* __restrict__ B,
                                                  const float* __restrict__ beta,
                                                  float* __restrict__ out) {
    extern __shared__ char ldsb[];   // 131072 bytes, dynamic

    const int tid    = threadIdx.x;
    const int wid    = tid >> 6;
    const int lane   = tid & 63;
    const int warp_m = wid >> 2;     // 0..1
    const int warp_n = wid & 3;      // 0..3
    const int lrow   = lane & 15;
    const int kgrp   = lane >> 4;

    // XCD-aware swizzle (grid = 256 = 8 XCDs x 32; 256 % 8 == 0 -> bijective)
    const int bid  = blockIdx.x;
    const int sbid = (bid & 7) * 32 + (bid >> 3);
    const int brow = (sbid >> 4) * BM;
    const int bcol = (sbid & 15) * BN;

    // ---- staging precompute: 2 chunks of 16B per thread per half-tile ----
    // physical LDS offset p (linear, lane-ordered for global_load_lds);
    // logical q = swz(p) determines which global element lands there.
    const int p0 = tid * 16, p1 = (tid + 512) * 16;
    const int q0 = swz(p0), q1 = swz(p1);
    const int rh0 = q0 >> 7, ce0 = (q0 & 127) >> 1;
    const int rh1 = q1 >> 7, ce1 = (q1 & 127) >> 1;

    const bf16_t* gA = A + (size_t)brow * KDIM;
    const bf16_t* gB = B + (size_t)bcol * KDIM;

    auto stageA = [&](int t, int h) {
        const int slot = ((t & 1) << 16) | (h << 14);
        GLDS16(gA + (size_t)(h * 128 + rh0) * KDIM + t * BK + ce0, ldsb + slot + p0);
        GLDS16(gA + (size_t)(h * 128 + rh1) * KDIM + t * BK + ce1, ldsb + slot + p1);
    };
    auto stageB = [&](int t, int h) {
        const int slot = ((t & 1) << 16) | ((2 + h) << 14);
        GLDS16(gB + (size_t)(h * 128 + rh0) * KDIM + t * BK + ce0, ldsb + slot + p0);
        GLDS16(gB + (size_t)(h * 128 + rh1) * KDIM + t * BK + ce1, ldsb + slot + p1);
    };

    // ---- ds_read offsets (swizzled), constant-indexed only ----
    int a_off[8][2];
#pragma unroll
    for (int mi = 0; mi < 8; ++mi)
#pragma unroll
        for (int ko = 0; ko < 2; ++ko)
            a_off[mi][ko] = (warp_m << 14) +
                swz((mi * 16 + lrow) * 128 + (ko * 32 + kgrp * 8) * 2);
    int b_off[4][2];
#pragma unroll
    for (int ni = 0; ni < 4; ++ni)
#pragma unroll
        for (int ko = 0; ko < 2; ++ko)
            b_off[ni][ko] = ((2 + (warp_n >> 1)) << 14) +
                swz(((warp_n & 1) * 64 + ni * 16 + lrow) * 128 + (ko * 32 + kgrp * 8) * 2);

    f32x4 acc[8][4];
#pragma unroll
    for (int i = 0; i < 8; ++i)
#pragma unroll
        for (int j = 0; j < 4; ++j)
            acc[i][j] = (f32x4){0.f, 0.f, 0.f, 0.f};

    bf16x8 av[4][2];   // current m-half: 4 rows x 2 ko
    bf16x8 bv[4][2];   // all 4 n-frags x 2 ko

    // ---- prologue: tile0 complete + A0/B0 of tile1 in flight ----
    stageA(0, 0); stageA(0, 1); stageB(0, 0); stageB(0, 1);
    stageA(1, 0); stageB(1, 0);
    VM4();           // retire tile 0 (keep A0(1),B0(1) in flight)
    BAR();

    for (int t = 0; t < NT; ++t) {
        const int buf = t & 1;
        // ---- P1: quadrant (m0..3, n0..1) ----
        LOAD_A_HALF(0, buf);
        LOAD_B_PAIR(0, buf);
        if (t + 1 < NT) stageA(t + 1, 1);
        BAR(); LGKM0();
        __builtin_amdgcn_s_setprio(1);
        MFMA_QUAD(0, 0);
        __builtin_amdgcn_s_setprio(0);
        BAR();
        // ---- P2: quadrant (m0..3, n2..3) ----
        LOAD_B_PAIR(1, buf);
        if (t + 1 < NT) stageB(t + 1, 1);
        BAR(); LGKM0();
        __builtin_amdgcn_s_setprio(1);
        MFMA_QUAD(0, 1);
        __builtin_amdgcn_s_setprio(0);
        BAR();
        // ---- P3: quadrant (m4..7, n0..1) ----
        LOAD_A_HALF(1, buf);
        if (t + 2 < NT) stageB(t + 2, 0);
        BAR(); LGKM0();
        __builtin_amdgcn_s_setprio(1);
        MFMA_QUAD(1, 0);
        __builtin_amdgcn_s_setprio(0);
        BAR();
        // ---- P4: quadrant (m4..7, n2..3) ----
        if (t + 2 < NT) stageA(t + 2, 0);
        BAR(); LGKM0();
        __builtin_amdgcn_s_setprio(1);
        MFMA_QUAD(1, 1);
        __builtin_amdgcn_s_setprio(0);
        if (t < NT - 2) { VM4(); } else { VM0(); }   // counted vmcnt, never mid-loop drain except tail
        BAR();
    }

    // ---- epilogue: relu(1 - beta + acc) ----
    const float bias = 1.0f - beta[0];
    float* outp = out + (size_t)(brow + warp_m * 128) * NDIM + bcol + warp_n * 64;
#pragma unroll
    for (int mi = 0; mi < 8; ++mi)
#pragma unroll
        for (int ni = 0; ni < 4; ++ni)
#pragma unroll
            for (int j = 0; j < 4; ++j) {
                const int r = mi * 16 + kgrp * 4 + j;   // C/D: row=(lane>>4)*4+reg
                const int c = ni * 16 + lrow;           //      col=lane&15
                outp[(size_t)r * NDIM + c] = fmaxf(acc[mi][ni][j] + bias, 0.0f);
            }
}

// ---------------- fp32 fallback (only if ws too small) ----------------
__global__ void gemm_f32_fallback(const float* __restrict__ A,
                                  const float* __restrict__ B,
                                  const float* __restrict__ beta,
                                  float* __restrict__ out) {
    __shared__ float sA[16][17];
    __shared__ float sB[16][17];
    const int tx = threadIdx.x, ty = threadIdx.y;
    const int m = blockIdx.y * 16 + ty;
    const int n = blockIdx.x * 16 + tx;
    float acc = 0.f;
    for (int k0 = 0; k0 < KDIM; k0 += 16) {
        sA[ty][tx] = A[(size_t)m * KDIM + k0 + tx];
        sB[ty][tx] = B[(size_t)(blockIdx.x * 16 + ty) * KDIM + k0 + tx];
        __syncthreads();
#pragma unroll
        for (int k = 0; k < 16; ++k)
            acc += sA[ty][k] * sB[tx][k];
        __syncthreads();
    }
    float v = acc + 1.0f - beta[0];
    out[(size_t)m * NDIM + n] = fmaxf(v, 0.f);
}

extern "C" void kernel_launch(void* const* d_in, const int* in_sizes, int n_in,
                              void* d_out, int out_size, void* d_ws, size_t ws_size,
                              hipStream_t stream) {
    const float* x    = (const float*)d_in[0];
    const float* w    = (const float*)d_in[1];
    const float* beta = (const float*)d_in[2];
    float* out        = (float*)d_out;

    const size_t nelem = (size_t)MDIM * (size_t)KDIM;   // per matrix
    const size_t need  = 2 * nelem * sizeof(bf16_t);    // 64 MB

    if (ws_size >= need) {
        bf16_t* xb = (bf16_t*)d_ws;
        bf16_t* wb = xb + nelem;
        // allow 128 KB dynamic LDS (idempotent, deterministic, capture-safe)
        hipFuncSetAttribute((const void*)gemm256,
                            hipFuncAttributeMaxDynamicSharedMemorySize, 131072);
        cvt_f32_to_bf16<<<2048, 256, 0, stream>>>(x, xb, (int)nelem);
        cvt_f32_to_bf16<<<2048, 256, 0, stream>>>(w, wb, (int)nelem);
        gemm256<<<256, 512, 131072, stream>>>(xb, wb, beta, out);
    } else {
        dim3 grid(NDIM / 16, MDIM / 16);
        gemm_f32_fallback<<<grid, dim3(16, 16), 0, stream>>>(x, w, beta, out);
    }
}

// Round 3
// 151.259 us; speedup vs baseline: 1.1840x; 1.0546x over previous
//
#include <hip/hip_runtime.h>
#include <hip/hip_bf16.h>
#include <cstdint>
#include <cstddef>

#define MDIM 4096
#define NDIM 4096
#define KDIM 4096

#define BM 256
#define BN 256
#define BK 64
#define NT (KDIM / BK)   // 64 K-tiles

typedef __bf16 bf16_t;
typedef bf16_t bf16x8 __attribute__((ext_vector_type(8)));
typedef float f32x4 __attribute__((ext_vector_type(4)));

#define GLDS16(gsrc, ldst)                                                   \
    __builtin_amdgcn_global_load_lds(                                        \
        (__attribute__((address_space(1))) void*)(gsrc),                     \
        (__attribute__((address_space(3))) void*)(ldst), 16, 0, 0)

#define BAR()   __builtin_amdgcn_s_barrier()
#define LGKM0() asm volatile("s_waitcnt lgkmcnt(0)" ::: "memory")
#define VM4()   asm volatile("s_waitcnt vmcnt(4)" ::: "memory")
#define VM0()   asm volatile("s_waitcnt vmcnt(0)" ::: "memory")

// Full 3-bit XOR swizzle for 128B-row tiles: byte ^= (row&7)<<4.
// Row bits 0-2 live at byte bits 7-9 (row stride 128B); XOR them into the
// 16B-slot index (byte bits 4-6). Involution, bijective per 1024B stripe.
// Spreads each kgrp's 16 rows across all 8 bank-groups -> b128 reads hit the
// 8-cycle minimum (round-2's single-bit version kept reads in 4/8 groups).
__device__ __forceinline__ int swz(int q) { return q ^ (((q >> 7) & 7) << 4); }

// ---------------- fp32 -> bf16 conversion pass ----------------
__global__ void cvt_f32_to_bf16(const float* __restrict__ src,
                                bf16_t* __restrict__ dst, int n) {
    int idx = (blockIdx.x * blockDim.x + threadIdx.x) * 8;
    int stride = gridDim.x * blockDim.x * 8;
    for (int i = idx; i < n; i += stride) {
        const float4* s = reinterpret_cast<const float4*>(src + i);
        float4 a = s[0];
        float4 b = s[1];
        bf16x8 o;
        o[0] = (bf16_t)a.x; o[1] = (bf16_t)a.y;
        o[2] = (bf16_t)a.z; o[3] = (bf16_t)a.w;
        o[4] = (bf16_t)b.x; o[5] = (bf16_t)b.y;
        o[6] = (bf16_t)b.z; o[7] = (bf16_t)b.w;
        *reinterpret_cast<bf16x8*>(dst + i) = o;
    }
}

// ---------------- 256x256 8-phase bf16 NT-GEMM ----------------
// C[m,n] = relu(1 - beta + sum_k A[m,k]*B[n,k]); A,B row-major [4096][4096] bf16.
// 512 threads = 8 waves (2M x 4N); each wave owns 128x64 output (8x4 frags of
// 16x16). LDS 128 KB: 2 dbuf x 4 half-slots (A0,A1,B0,B1) x 128x64 bf16.
// Per K-tile: 4 phases; per phase: {ds_reads, 1 half-tile stage, BAR, lgkm0,
// setprio(1), 16 MFMA, setprio(0), [vmcnt @P4], BAR}.
// Rolling prefetch, window t stages: P1:A1(t+1) P2:B1(t+1) P3:B0(t+2) P4:A0(t+2).

#define LOAD_A_HALF(MH, BUF) do {                                            \
  _Pragma("unroll") for (int mi = 0; mi < 4; ++mi)                           \
  _Pragma("unroll") for (int ko = 0; ko < 2; ++ko)                           \
    av[mi][ko] = *(const bf16x8*)(ldsb + ((BUF) << 16) + a_off[(MH)*4 + mi][ko]); \
} while (0)

#define LOAD_B_PAIR(NH, BUF) do {                                            \
  _Pragma("unroll") for (int ni = 0; ni < 2; ++ni)                           \
  _Pragma("unroll") for (int ko = 0; ko < 2; ++ko)                           \
    bv[(NH)*2 + ni][ko] = *(const bf16x8*)(ldsb + ((BUF) << 16) + b_off[(NH)*2 + ni][ko]); \
} while (0)

#define MFMA_QUAD(MH, NH) do {                                               \
  _Pragma("unroll") for (int mi = 0; mi < 4; ++mi)                           \
  _Pragma("unroll") for (int ni = 0; ni < 2; ++ni)                           \
  _Pragma("unroll") for (int ko = 0; ko < 2; ++ko)                           \
    acc[(MH)*4 + mi][(NH)*2 + ni] = __builtin_amdgcn_mfma_f32_16x16x32_bf16( \
        av[mi][ko], bv[(NH)*2 + ni][ko], acc[(MH)*4 + mi][(NH)*2 + ni], 0, 0, 0); \
} while (0)

__global__ __launch_bounds__(512, 2) void gemm256(const bf16_t* __restrict__ A,
                                                  const bf16_t* __restrict__ B,
                                                  const float* __restrict__ beta,
                                                  float* __restrict__ out) {
    extern __shared__ char ldsb[];   // 131072 bytes, dynamic

    const int tid    = threadIdx.x;
    const int wid    = tid >> 6;
    const int lane   = tid & 63;
    const int warp_m = wid >> 2;     // 0..1
    const int warp_n = wid & 3;      // 0..3
    const int lrow   = lane & 15;
    const int kgrp   = lane >> 4;

    // XCD-aware swizzle (grid = 256 = 8 XCDs x 32; 256 % 8 == 0 -> bijective)
    const int bid  = blockIdx.x;
    const int sbid = (bid & 7) * 32 + (bid >> 3);
    const int brow = (sbid >> 4) * BM;
    const int bcol = (sbid & 15) * BN;

    // ---- staging precompute: 2 chunks of 16B per thread per half-tile ----
    // physical LDS offset p (linear, lane-ordered for global_load_lds);
    // logical q = swz(p) determines which global element lands there.
    const int p0 = tid * 16, p1 = (tid + 512) * 16;
    const int q0 = swz(p0), q1 = swz(p1);
    const int rh0 = q0 >> 7, ce0 = (q0 & 127) >> 1;
    const int rh1 = q1 >> 7, ce1 = (q1 & 127) >> 1;

    const bf16_t* gA = A + (size_t)brow * KDIM;
    const bf16_t* gB = B + (size_t)bcol * KDIM;

    auto stageA = [&](int t, int h) {
        const int slot = ((t & 1) << 16) | (h << 14);
        GLDS16(gA + (size_t)(h * 128 + rh0) * KDIM + t * BK + ce0, ldsb + slot + p0);
        GLDS16(gA + (size_t)(h * 128 + rh1) * KDIM + t * BK + ce1, ldsb + slot + p1);
    };
    auto stageB = [&](int t, int h) {
        const int slot = ((t & 1) << 16) | ((2 + h) << 14);
        GLDS16(gB + (size_t)(h * 128 + rh0) * KDIM + t * BK + ce0, ldsb + slot + p0);
        GLDS16(gB + (size_t)(h * 128 + rh1) * KDIM + t * BK + ce1, ldsb + slot + p1);
    };

    // ---- ds_read offsets (swizzled), constant-indexed only ----
    int a_off[8][2];
#pragma unroll
    for (int mi = 0; mi < 8; ++mi)
#pragma unroll
        for (int ko = 0; ko < 2; ++ko)
            a_off[mi][ko] = (warp_m << 14) +
                swz((mi * 16 + lrow) * 128 + (ko * 32 + kgrp * 8) * 2);
    int b_off[4][2];
#pragma unroll
    for (int ni = 0; ni < 4; ++ni)
#pragma unroll
        for (int ko = 0; ko < 2; ++ko)
            b_off[ni][ko] = ((2 + (warp_n >> 1)) << 14) +
                swz(((warp_n & 1) * 64 + ni * 16 + lrow) * 128 + (ko * 32 + kgrp * 8) * 2);

    f32x4 acc[8][4];
#pragma unroll
    for (int i = 0; i < 8; ++i)
#pragma unroll
        for (int j = 0; j < 4; ++j)
            acc[i][j] = (f32x4){0.f, 0.f, 0.f, 0.f};

    bf16x8 av[4][2];   // current m-half: 4 rows x 2 ko
    bf16x8 bv[4][2];   // all 4 n-frags x 2 ko

    // ---- prologue: tile0 complete + A0/B0 of tile1 in flight ----
    stageA(0, 0); stageA(0, 1); stageB(0, 0); stageB(0, 1);
    stageA(1, 0); stageB(1, 0);
    VM4();           // retire tile 0 (keep A0(1),B0(1) in flight)
    BAR();

    for (int t = 0; t < NT; ++t) {
        const int buf = t & 1;
        // ---- P1: quadrant (m0..3, n0..1) ----
        LOAD_A_HALF(0, buf);
        LOAD_B_PAIR(0, buf);
        if (t + 1 < NT) stageA(t + 1, 1);
        BAR(); LGKM0();
        __builtin_amdgcn_s_setprio(1);
        MFMA_QUAD(0, 0);
        __builtin_amdgcn_s_setprio(0);
        BAR();
        // ---- P2: quadrant (m0..3, n2..3) ----
        LOAD_B_PAIR(1, buf);
        if (t + 1 < NT) stageB(t + 1, 1);
        BAR(); LGKM0();
        __builtin_amdgcn_s_setprio(1);
        MFMA_QUAD(0, 1);
        __builtin_amdgcn_s_setprio(0);
        BAR();
        // ---- P3: quadrant (m4..7, n0..1) ----
        LOAD_A_HALF(1, buf);
        if (t + 2 < NT) stageB(t + 2, 0);
        BAR(); LGKM0();
        __builtin_amdgcn_s_setprio(1);
        MFMA_QUAD(1, 0);
        __builtin_amdgcn_s_setprio(0);
        BAR();
        // ---- P4: quadrant (m4..7, n2..3) ----
        if (t + 2 < NT) stageA(t + 2, 0);
        BAR(); LGKM0();
        __builtin_amdgcn_s_setprio(1);
        MFMA_QUAD(1, 1);
        __builtin_amdgcn_s_setprio(0);
        if (t < NT - 2) { VM4(); } else { VM0(); }   // counted vmcnt, never mid-loop drain except tail
        BAR();
    }

    // ---- epilogue: relu(1 - beta + acc) ----
    const float bias = 1.0f - beta[0];
    float* outp = out + (size_t)(brow + warp_m * 128) * NDIM + bcol + warp_n * 64;
#pragma unroll
    for (int mi = 0; mi < 8; ++mi)
#pragma unroll
        for (int ni = 0; ni < 4; ++ni)
#pragma unroll
            for (int j = 0; j < 4; ++j) {
                const int r = mi * 16 + kgrp * 4 + j;   // C/D: row=(lane>>4)*4+reg
                const int c = ni * 16 + lrow;           //      col=lane&15
                outp[(size_t)r * NDIM + c] = fmaxf(acc[mi][ni][j] + bias, 0.0f);
            }
}

// ---------------- fp32 fallback (only if ws too small) ----------------
__global__ void gemm_f32_fallback(const float* __restrict__ A,
                                  const float* __restrict__ B,
                                  const float* __restrict__ beta,
                                  float* __restrict__ out) {
    __shared__ float sA[16][17];
    __shared__ float sB[16][17];
    const int tx = threadIdx.x, ty = threadIdx.y;
    const int m = blockIdx.y * 16 + ty;
    const int n = blockIdx.x * 16 + tx;
    float acc = 0.f;
    for (int k0 = 0; k0 < KDIM; k0 += 16) {
        sA[ty][tx] = A[(size_t)m * KDIM + k0 + tx];
        sB[ty][tx] = B[(size_t)(blockIdx.x * 16 + ty) * KDIM + k0 + tx];
        __syncthreads();
#pragma unroll
        for (int k = 0; k < 16; ++k)
            acc += sA[ty][k] * sB[tx][k];
        __syncthreads();
    }
    float v = acc + 1.0f - beta[0];
    out[(size_t)m * NDIM + n] = fmaxf(v, 0.f);
}

extern "C" void kernel_launch(void* const* d_in, const int* in_sizes, int n_in,
                              void* d_out, int out_size, void* d_ws, size_t ws_size,
                              hipStream_t stream) {
    const float* x    = (const float*)d_in[0];
    const float* w    = (const float*)d_in[1];
    const float* beta = (const float*)d_in[2];
    float* out        = (float*)d_out;

    const size_t nelem = (size_t)MDIM * (size_t)KDIM;   // per matrix
    const size_t need  = 2 * nelem * sizeof(bf16_t);    // 64 MB

    if (ws_size >= need) {
        bf16_t* xb = (bf16_t*)d_ws;
        bf16_t* wb = xb + nelem;
        // allow 128 KB dynamic LDS (idempotent, deterministic, capture-safe)
        hipFuncSetAttribute((const void*)gemm256,
                            hipFuncAttributeMaxDynamicSharedMemorySize, 131072);
        cvt_f32_to_bf16<<<2048, 256, 0, stream>>>(x, xb, (int)nelem);
        cvt_f32_to_bf16<<<2048, 256, 0, stream>>>(w, wb, (int)nelem);
        gemm256<<<256, 512, 131072, stream>>>(xb, wb, beta, out);
    } else {
        dim3 grid(NDIM / 16, MDIM / 16);
        gemm_f32_fallback<<<grid, dim3(16, 16), 0, stream>>>(x, w, beta, out);
    }
}